// Round 8
// baseline (4155.537 us; speedup 1.0000x reference)
//
#include <hip/hip_runtime.h>
#include <stdint.h>

#define TLEN 1024
#define BATCH 64
#define DIMX 128
#define HID 512

typedef __attribute__((ext_vector_type(8))) short short8;
typedef __attribute__((ext_vector_type(4))) float f32x4;
typedef __attribute__((ext_vector_type(4))) unsigned u32x4;

// ---- workspace layout (bytes) ----
#define OFF_WT   0u           // Wt: [2048][640] bf16 = 2,621,440
#define OFF_XBF  2621440u     // xbf: [64][1024][128] bf16 = 16,777,216
#define OFF_HB   19398656u    // hb: [2][64][512] u32 (tagged bf16) = 262,144
#define OFF_ACC  19660800u    // acc: 64
#define ZERO_LEN (262144u + 64u)

__device__ __forceinline__ unsigned short f2bf(float f) {
  unsigned u = __float_as_uint(f);
  u += 0x7fffu + ((u >> 16) & 1u);
  return (unsigned short)(u >> 16);
}
__device__ __forceinline__ float sigm(float x) { return 1.0f / (1.0f + __expf(-x)); }
__device__ __forceinline__ float tanh_fast(float x) {
  float a = fabsf(x);
  float e = __expf(2.0f * a);
  float t = 1.0f - 2.0f / (e + 1.0f);
  return copysignf(t, x);
}

// ---- x fp32 -> bf16, coalesced ----
__global__ void k_convx(const float4* __restrict__ x4, ushort4* __restrict__ o4) {
  int i = blockIdx.x * 256 + threadIdx.x;
  float4 v = x4[i];
  ushort4 o;
  o.x = f2bf(v.x); o.y = f2bf(v.y); o.z = f2bf(v.z); o.w = f2bf(v.w);
  o4[i] = o;
}

// ---- build Wt[col 0..2047][k 0..639] bf16 = concat(Wx;Wh)^T (proven) ----
__global__ void k_tw(const float* __restrict__ Wx, const float* __restrict__ Wh,
                     unsigned short* __restrict__ Wt) {
  __shared__ float tile[32][65];
  int bk = blockIdx.x;
  int k0 = (bk / 64) * 64;
  int c0 = (bk % 64) * 32;
  int tid = threadIdx.x;
  const float* src = (k0 < 128) ? (Wx + (size_t)k0 * 2048)
                                : (Wh + (size_t)(k0 - 128) * 2048);
#pragma unroll
  for (int p = 0; p < 8; ++p) {
    int i = p * 256 + tid;
    int kk = i >> 5, cc = i & 31;
    tile[cc][kk] = src[(size_t)kk * 2048 + (c0 + cc)];
  }
  __syncthreads();
  int cc = tid >> 3, ch = tid & 7;
  unsigned short tmp[8];
#pragma unroll
  for (int j = 0; j < 8; ++j) tmp[j] = f2bf(tile[cc][ch * 8 + j]);
  uint4 o;
  o.x = (unsigned)tmp[0] | ((unsigned)tmp[1] << 16);
  o.y = (unsigned)tmp[2] | ((unsigned)tmp[3] << 16);
  o.z = (unsigned)tmp[4] | ((unsigned)tmp[5] << 16);
  o.w = (unsigned)tmp[6] | ((unsigned)tmp[7] << 16);
  *(uint4*)(Wt + (size_t)(c0 + cc) * 640 + k0 + ch * 8) = o;
}

// ---- recurrence: 64 WGs = 8 groups(8 rows) x 8 WGs(256thr = 4 waves) ----
// Fat WGs: 64 h-cols each, 320 weight-VGPRs/lane, 1 wave/SIMD. Wave = K-slice.
__global__ __launch_bounds__(256, 1) void k_lstm(
    const unsigned short* __restrict__ xbf,   // [B][T][D] bf16
    const unsigned short* __restrict__ Wt,    // [4H][640] bf16 (B^T layout)
    const float* __restrict__ bias,           // [4H]
    const float* __restrict__ Wo,             // [H][2]
    unsigned* __restrict__ hb,                // [2][B][H] tagged u32
    float* __restrict__ out)                  // [B][T][2] logits via atomicAdd
{
  __shared__ float red[2][4][4][8][16][4];  // [buf][kw][hc4][row][m][gate] 64KB

  const int tid  = threadIdx.x;
  const int kw   = tid >> 6;      // wave 0..3 = K-slice
  const int lane = tid & 63;
  const int q    = lane >> 4;
  const int m    = lane & 15;
  const int grp  = blockIdx.x & 7;   // group -> XCD (heuristic, perf only)
  const int hj   = blockIdx.x >> 3;  // 0..7: owns h cols hj*64..+63
  const int g0   = grp * 8;

  // ---- pin weight slice: Bf[c][j], j = hc4*4 + gate (gate fastest) ----
  short8 Bf[5][16];
#pragma unroll
  for (int c = 0; c < 5; ++c) {
#pragma unroll
    for (int j = 0; j < 16; ++j) {
      int gate = j & 3, hc4 = j >> 2;
      int col = gate * HID + hj * 64 + hc4 * 16 + m;
      int k = (c == 0) ? (kw * 32 + q * 8)
                       : (128 + kw * 128 + (c - 1) * 32 + q * 8);
      Bf[c][j] = *(const short8*)(Wt + (size_t)col * 640 + k);
    }
  }

  // gate duty: thread owns (row = tid>>5, cells hp and hp+32), hp = tid&31
  const int grow = tid >> 5;
  const int hp   = tid & 31;
  const int hcA  = hj * 64 + hp;        // cell 0 global h-col
  const int hcB  = hcA + 32;            // cell 1
  float cstA = 0.f, cstB = 0.f;
  const float biA = bias[0 * HID + hcA], biB = bias[0 * HID + hcB];
  const float bfA = bias[1 * HID + hcA], bfB = bias[1 * HID + hcB];
  const float bgA = bias[2 * HID + hcA], bgB = bias[2 * HID + hcB];
  const float boA = bias[3 * HID + hcA], boB = bias[3 * HID + hcB];
  const float2 woA = ((const float2*)Wo)[hcA];
  const float2 woB = ((const float2*)Wo)[hcB];
  const int hc4A = hp >> 4;             // 0..1 (local 16-col tile of cell0)
  const int mA   = hp & 15;

  const int ab = g0 + (m & 7);   // A rows 8..15 duplicate rows 0..7 (discarded)

#pragma unroll 1
  for (int t = 0; t < TLEN; ++t) {
    const unsigned* hin = hb + (size_t)(t & 1) * (BATCH * HID);
    const int buf = t & 1;

    // ---- x chunk (plain cached load, L2-shared within group) ----
    short8 a0 = *(const short8*)(xbf + ((size_t)ab * TLEN + t) * DIMX +
                                 kw * 32 + q * 8);

    // ---- h window [kw*128..+128): batched bypass poll, detect==data ----
    const unsigned* pb = hin + (size_t)ab * HID + kw * 128 + q * 8;
    u32x4 r0, r1, r2, r3, r4, r5, r6, r7;
    {
      const unsigned tg = (unsigned)t & 0xFFFFu;
      int guard = 0;
      for (;;) {
        asm volatile(
            "global_load_dwordx4 %0, %8, off sc0 sc1\n\t"
            "global_load_dwordx4 %1, %8, off offset:16 sc0 sc1\n\t"
            "global_load_dwordx4 %2, %8, off offset:128 sc0 sc1\n\t"
            "global_load_dwordx4 %3, %8, off offset:144 sc0 sc1\n\t"
            "global_load_dwordx4 %4, %8, off offset:256 sc0 sc1\n\t"
            "global_load_dwordx4 %5, %8, off offset:272 sc0 sc1\n\t"
            "global_load_dwordx4 %6, %8, off offset:384 sc0 sc1\n\t"
            "global_load_dwordx4 %7, %8, off offset:400 sc0 sc1\n\t"
            "s_waitcnt vmcnt(0)"
            : "=v"(r0), "=v"(r1), "=v"(r2), "=v"(r3),
              "=v"(r4), "=v"(r5), "=v"(r6), "=v"(r7)
            : "v"(pb)
            : "memory");
        unsigned d = (r0[0] ^ tg) | (r0[1] ^ tg) | (r0[2] ^ tg) | (r0[3] ^ tg);
        d |= (r1[0] ^ tg) | (r1[1] ^ tg) | (r1[2] ^ tg) | (r1[3] ^ tg);
        d |= (r2[0] ^ tg) | (r2[1] ^ tg) | (r2[2] ^ tg) | (r2[3] ^ tg);
        d |= (r3[0] ^ tg) | (r3[1] ^ tg) | (r3[2] ^ tg) | (r3[3] ^ tg);
        d |= (r4[0] ^ tg) | (r4[1] ^ tg) | (r4[2] ^ tg) | (r4[3] ^ tg);
        d |= (r5[0] ^ tg) | (r5[1] ^ tg) | (r5[2] ^ tg) | (r5[3] ^ tg);
        d |= (r6[0] ^ tg) | (r6[1] ^ tg) | (r6[2] ^ tg) | (r6[3] ^ tg);
        d |= (r7[0] ^ tg) | (r7[1] ^ tg) | (r7[2] ^ tg) | (r7[3] ^ tg);
        bool bad = (d & 0xFFFFu) != 0u;
        if (__ballot(bad) == 0ull || ++guard > (1 << 20)) break;
      }
    }

    // ---- pack tagged words -> bf16 A fragments ----
    short8 a[5];
    a[0] = a0;
    {
      union { short8 s; unsigned u[4]; } pk;
#define PACK(dst, RA, RB)                                            \
      pk.u[0] = (RA[0] >> 16) | (RA[1] & 0xFFFF0000u);               \
      pk.u[1] = (RA[2] >> 16) | (RA[3] & 0xFFFF0000u);               \
      pk.u[2] = (RB[0] >> 16) | (RB[1] & 0xFFFF0000u);               \
      pk.u[3] = (RB[2] >> 16) | (RB[3] & 0xFFFF0000u);               \
      dst = pk.s;
      PACK(a[1], r0, r1)
      PACK(a[2], r2, r3)
      PACK(a[3], r4, r5)
      PACK(a[4], r6, r7)
#undef PACK
    }

    // ---- MFMA: 5 K-frags x 16 N-frags, 16 parallel acc chains ----
    f32x4 acc[16];
#pragma unroll
    for (int j = 0; j < 16; ++j) acc[j] = (f32x4){0.f, 0.f, 0.f, 0.f};
#pragma unroll
    for (int c = 0; c < 5; ++c) {
#pragma unroll
      for (int j = 0; j < 16; ++j)
        acc[j] = __builtin_amdgcn_mfma_f32_16x16x32_bf16(a[c], Bf[c][j], acc[j],
                                                         0, 0, 0);
    }

    // ---- stage partials (rows 0..7 live in quads 0,1), b128 writes ----
    if (q < 2) {
#pragma unroll
      for (int hc4 = 0; hc4 < 4; ++hc4) {
#pragma unroll
        for (int r = 0; r < 4; ++r) {
          f32x4 v = {acc[hc4 * 4 + 0][r], acc[hc4 * 4 + 1][r],
                     acc[hc4 * 4 + 2][r], acc[hc4 * 4 + 3][r]};
          *(f32x4*)&red[buf][kw][hc4][q * 4 + r][m][0] = v;
        }
      }
    }
    __syncthreads();   // the only rendezvous per step

    // ---- gates for 2 cells + tagged h store + logit duty ----
    {
      f32x4 zA = {biA, bfA, bgA, boA};
      f32x4 zB = {biB, bfB, bgB, boB};
#pragma unroll
      for (int k2 = 0; k2 < 4; ++k2) {
        zA += *(const f32x4*)&red[buf][k2][hc4A][grow][mA][0];
        zB += *(const f32x4*)&red[buf][k2][hc4A + 2][grow][mA][0];
      }
      float igA = sigm(zA[0]), fgA = sigm(zA[1]);
      float ggA = tanh_fast(zA[2]), ogA = sigm(zA[3]);
      cstA = fgA * cstA + igA * ggA;
      float hA = ogA * tanh_fast(cstA);
      float igB = sigm(zB[0]), fgB = sigm(zB[1]);
      float ggB = tanh_fast(zB[2]), ogB = sigm(zB[3]);
      cstB = fgB * cstB + igB * ggB;
      float hB = ogB * tanh_fast(cstB);

      unsigned tg1 = (unsigned)((t + 1) & 0xFFFF);
      unsigned hwA = ((unsigned)f2bf(hA) << 16) | tg1;
      unsigned hwB = ((unsigned)f2bf(hB) << 16) | tg1;

      // gather 4 consecutive cols -> dwordx4 stores (2 per quad leader)
      int bse = lane & ~3;
      unsigned a0s = __shfl(hwA, bse + 0), a1s = __shfl(hwA, bse + 1);
      unsigned a2s = __shfl(hwA, bse + 2), a3s = __shfl(hwA, bse + 3);
      unsigned b0s = __shfl(hwB, bse + 0), b1s = __shfl(hwB, bse + 1);
      unsigned b2s = __shfl(hwB, bse + 2), b3s = __shfl(hwB, bse + 3);
      if ((lane & 3) == 0) {
        unsigned* dst = hb + (size_t)((t + 1) & 1) * (BATCH * HID) +
                        (size_t)(g0 + grow) * HID + hcA;
        u32x4 vA = {a0s, a1s, a2s, a3s};
        u32x4 vB = {b0s, b1s, b2s, b3s};
        asm volatile("global_store_dwordx4 %0, %1, off sc0 sc1"
                     :: "v"(dst), "v"(vA) : "memory");
        asm volatile("global_store_dwordx4 %0, %1, off sc0 sc1"
                     :: "v"(dst + 32), "v"(vB) : "memory");
      }

      // logit partials (fire-and-forget atomics, off critical path)
      float p0 = hA * woA.x + hB * woB.x;
      float p1 = hA * woA.y + hB * woB.y;
      p0 += __shfl_xor(p0, 1);  p1 += __shfl_xor(p1, 1);
      p0 += __shfl_xor(p0, 2);  p1 += __shfl_xor(p1, 2);
      p0 += __shfl_xor(p0, 4);  p1 += __shfl_xor(p1, 4);
      p0 += __shfl_xor(p0, 8);  p1 += __shfl_xor(p1, 8);
      p0 += __shfl_xor(p0, 16); p1 += __shfl_xor(p1, 16);
      if ((lane & 31) == 0) {
        float* po = out + ((size_t)(g0 + grow) * TLEN + t) * 2;
        atomicAdd(po + 0, p0);
        atomicAdd(po + 1, p1);
      }
    }
  }
}

// ---- logits -> softmax probs + NLL ----
__global__ void k_out2(float* __restrict__ out, const float* __restrict__ bo,
                       const int* __restrict__ labels, float* __restrict__ acc) {
  __shared__ float sred[4];
  int i = blockIdx.x * 256 + threadIdx.x;   // 0..65535 = b*T + t
  float l0 = out[(size_t)i * 2 + 0] + bo[0];
  float l1 = out[(size_t)i * 2 + 1] + bo[1];
  float mx = fmaxf(l0, l1);
  float e0 = __expf(l0 - mx), e1 = __expf(l1 - mx);
  float s = e0 + e1, inv = 1.0f / s;
  out[(size_t)i * 2 + 0] = e0 * inv;
  out[(size_t)i * 2 + 1] = e1 * inv;
  int lab = labels[i];
  float nll = __logf(s) - ((lab ? l1 : l0) - mx);
#pragma unroll
  for (int off = 32; off >= 1; off >>= 1) nll += __shfl_xor(nll, off);
  if ((threadIdx.x & 63) == 0) sred[threadIdx.x >> 6] = nll;
  __syncthreads();
  if (threadIdx.x == 0)
    atomicAdd(acc, sred[0] + sred[1] + sred[2] + sred[3]);
}

__global__ void k_fin(const float* __restrict__ acc, float* __restrict__ out) {
  out[BATCH * TLEN * 2] = acc[0] * (1.0f / (float)(BATCH * TLEN));
}

extern "C" void kernel_launch(void* const* d_in, const int* in_sizes, int n_in,
                              void* d_out, int out_size, void* d_ws, size_t ws_size,
                              hipStream_t stream) {
  const float* x      = (const float*)d_in[0];
  const int*   labels = (const int*)d_in[1];
  const float* Wx     = (const float*)d_in[2];
  const float* Wh     = (const float*)d_in[3];
  const float* b      = (const float*)d_in[4];
  const float* Wo     = (const float*)d_in[5];
  const float* bo     = (const float*)d_in[6];
  float* out = (float*)d_out;
  char* ws = (char*)d_ws;

  unsigned short* Wt  = (unsigned short*)(ws + OFF_WT);
  unsigned short* xbf = (unsigned short*)(ws + OFF_XBF);
  unsigned*       hb  = (unsigned*)(ws + OFF_HB);
  float*          acc = (float*)(ws + OFF_ACC);

  // hb zero => h_0 = 0 with tag 0 (self-validating); acc zero; out zero
  hipMemsetAsync(ws + OFF_HB, 0, ZERO_LEN, stream);
  hipMemsetAsync(d_out, 0, (size_t)BATCH * TLEN * 2 * sizeof(float), stream);
  k_convx<<<8192, 256, 0, stream>>>((const float4*)x, (ushort4*)xbf);
  k_tw<<<640, 256, 0, stream>>>(Wx, Wh, Wt);
  k_lstm<<<64, 256, 0, stream>>>(xbf, Wt, b, Wo, hb, out);
  k_out2<<<256, 256, 0, stream>>>(out, bo, labels, acc);
  k_fin<<<1, 1, 0, stream>>>(acc, out);
}